// Round 9
// baseline (25.679 us; speedup 1.0000x reference)
//
#include <hip/hip_runtime.h>

// Problem constants (from reference setup_inputs)
#define N_  8
#define K_  32
#define TK_ 128
#define TC_ 256
#define D_  512
#define D4_ (D_ / 4)               // 128 float4 per emb row
#define TOUT_ (TK_ + TC_)          // 384
#define NEGINF_ (-1e20f)
#define INV_SQRT_D_ 0.044194173824159216f   // 1/sqrt(512)

// d_out layout (float): full_enc [N,384,512] | full_mask [N,384] | ck_attn [N,32]
#define OUT_MASK_OFF_ 1572864
#define OUT_ATTN_OFF_ 1575936

#define QPC_ 16                     // ctx slices per row
#define QTOK_ (TC_ / QPC_)          // 16 tokens per slice
#define POOLB_ (N_ * QPC_)          // 128 pool blocks

// ---------------------------------------------------------------
// Kernel 1 (128 blocks x 1024): block (n,q) handles ctx tokens
// [q*16,(q+1)*16): pools into partial[n*16+q] (+count) AND writes those
// full_enc context rows + full_mask while the rows are in registers.
// Block 0 resets key[].
__global__ __launch_bounds__(1024) void ctx_pool_kernel(
        const int* __restrict__ src_tokens,
        const float* __restrict__ emb,
        float* __restrict__ full_enc,
        float* __restrict__ full_mask,
        float4* __restrict__ partial,        // [128][128] float4
        int* __restrict__ pcnt,              // [128]
        unsigned long long* __restrict__ key) {
    const int bid = blockIdx.x;
    const int n = bid >> 4, q = bid & 15;
    const int tid = threadIdx.x;
    const int tg = tid >> 7, lane = tid & 127;
    const float4* emb4 = (const float4*)emb;

    __shared__ int s_tok[QTOK_];
    __shared__ float4 s_red[8][D4_];   // 16 KB
    __shared__ int s_cnt[8];

    if (bid == 0 && tid < N_) key[tid] = 0ull;   // per-call reset
    if (tid < QTOK_) s_tok[tid] = src_tokens[n * TC_ + q * QTOK_ + tid];
    __syncthreads();

    float4 acc = make_float4(0.f, 0.f, 0.f, 0.f);
    int cnt = 0;
    #pragma unroll
    for (int i = 0; i < QTOK_ / 8; ++i) {        // 2 tokens per thread
        const int t = tg + i * 8;                // token slot within slice
        const int tok = s_tok[t];
        const float4 v = emb4[(size_t)tok * D4_ + lane];  // row 0 is valid
        // write-through to full_enc context region (emb[tok] regardless of pad)
        const int row = TK_ + q * QTOK_ + t;
        ((float4*)(full_enc + ((size_t)n * TOUT_ + row) * D_))[lane] = v;
        if (lane == 0) full_mask[n * TOUT_ + row] = (tok != 0) ? 1.0f : 0.0f;

        const bool use = (tok != 0);
        cnt += use ? 1 : 0;
        acc.x += use ? v.x : 0.f;
        acc.y += use ? v.y : 0.f;
        acc.z += use ? v.z : 0.f;
        acc.w += use ? v.w : 0.f;
    }
    s_red[tg][lane] = acc;
    if (lane == 0) s_cnt[tg] = cnt;
    __syncthreads();

    if (tg == 0) {
        float4 tot = s_red[0][lane];
        #pragma unroll
        for (int j = 1; j < 8; ++j) {
            const float4 v = s_red[j][lane];
            tot.x += v.x; tot.y += v.y; tot.z += v.z; tot.w += v.w;
        }
        partial[bid * D4_ + lane] = tot;
        if (lane == 0) {
            int c = 0;
            #pragma unroll
            for (int j = 0; j < 8; ++j) c += s_cnt[j];
            pcnt[bid] = c;
        }
    }
}

// ---------------------------------------------------------------
// Kernel 2 (256 blocks x 1024): block (n,k) = fused knowledge pool+dot.
// Inner loop: explicit 8-wide load batches (8 loads in flight, 8 separate
// accumulators) to force memory-level parallelism in the emb gather.
__global__ __launch_bounds__(1024) void know_kernel(
        const int* __restrict__ know_tokens,
        const int* __restrict__ ck_mask,
        const float* __restrict__ emb,
        const float4* __restrict__ partial,
        const int* __restrict__ pcnt,
        float* __restrict__ ck_attn,
        unsigned long long* __restrict__ key) {
    const int bid = blockIdx.x;
    const int tid = threadIdx.x;
    const int n = bid >> 5, k = bid & 31;
    const int tg = tid >> 7, lane = tid & 127;
    const float4* emb4 = (const float4*)emb;

    __shared__ float4 s_ctx[D4_];    // 2 KB
    __shared__ int s_tok[TK_];
    __shared__ float s_part[16];
    __shared__ int s_bcnt[2];

    if (tid < D4_) {
        // combine the 16 ctx partials -> scaled ctx_use slice
        float4 c = partial[(n * QPC_ + 0) * D4_ + tid];
        int cc = pcnt[n * QPC_ + 0];
        #pragma unroll
        for (int qq = 1; qq < QPC_; ++qq) {
            const float4 v = partial[(n * QPC_ + qq) * D4_ + tid];
            c.x += v.x; c.y += v.y; c.z += v.z; c.w += v.w;
            cc += pcnt[n * QPC_ + qq];
        }
        const float sc = INV_SQRT_D_ / sqrtf((float)cc);
        c.x *= sc; c.y *= sc; c.z *= sc; c.w *= sc;
        s_ctx[tid] = c;

        const int tok = know_tokens[(size_t)bid * TK_ + tid];
        s_tok[tid] = tok;
        const unsigned long long b = __ballot(tok != 0);   // waves 0,1 full
        if ((tid & 63) == 0) s_bcnt[tid >> 6] = (int)__popcll(b);
    }
    __syncthreads();

    const float4 c = s_ctx[lane];
    float a0 = 0.f, a1 = 0.f, a2 = 0.f, a3 = 0.f;
    float a4 = 0.f, a5 = 0.f, a6 = 0.f, a7 = 0.f;
    #pragma unroll
    for (int i = 0; i < 2; ++i) {                // 16 tokens/thread, 8 in flight
        const int t0 = s_tok[tg + (i * 8 + 0) * 8];
        const int t1 = s_tok[tg + (i * 8 + 1) * 8];
        const int t2 = s_tok[tg + (i * 8 + 2) * 8];
        const int t3 = s_tok[tg + (i * 8 + 3) * 8];
        const int t4 = s_tok[tg + (i * 8 + 4) * 8];
        const int t5 = s_tok[tg + (i * 8 + 5) * 8];
        const int t6 = s_tok[tg + (i * 8 + 6) * 8];
        const int t7 = s_tok[tg + (i * 8 + 7) * 8];
        const float4 v0 = emb4[(size_t)t0 * D4_ + lane];
        const float4 v1 = emb4[(size_t)t1 * D4_ + lane];
        const float4 v2 = emb4[(size_t)t2 * D4_ + lane];
        const float4 v3 = emb4[(size_t)t3 * D4_ + lane];
        const float4 v4 = emb4[(size_t)t4 * D4_ + lane];
        const float4 v5 = emb4[(size_t)t5 * D4_ + lane];
        const float4 v6 = emb4[(size_t)t6 * D4_ + lane];
        const float4 v7 = emb4[(size_t)t7 * D4_ + lane];
        a0 += (t0 != 0) ? (v0.x*c.x + v0.y*c.y + v0.z*c.z + v0.w*c.w) : 0.f;
        a1 += (t1 != 0) ? (v1.x*c.x + v1.y*c.y + v1.z*c.z + v1.w*c.w) : 0.f;
        a2 += (t2 != 0) ? (v2.x*c.x + v2.y*c.y + v2.z*c.z + v2.w*c.w) : 0.f;
        a3 += (t3 != 0) ? (v3.x*c.x + v3.y*c.y + v3.z*c.z + v3.w*c.w) : 0.f;
        a4 += (t4 != 0) ? (v4.x*c.x + v4.y*c.y + v4.z*c.z + v4.w*c.w) : 0.f;
        a5 += (t5 != 0) ? (v5.x*c.x + v5.y*c.y + v5.z*c.z + v5.w*c.w) : 0.f;
        a6 += (t6 != 0) ? (v6.x*c.x + v6.y*c.y + v6.z*c.z + v6.w*c.w) : 0.f;
        a7 += (t7 != 0) ? (v7.x*c.x + v7.y*c.y + v7.z*c.z + v7.w*c.w) : 0.f;
    }
    float acc = ((a0 + a1) + (a2 + a3)) + ((a4 + a5) + (a6 + a7));
    #pragma unroll
    for (int off = 32; off > 0; off >>= 1) acc += __shfl_down(acc, off, 64);
    if ((tid & 63) == 0) s_part[tid >> 6] = acc;
    __syncthreads();

    if (tid == 0) {
        float v = 0.f;
        #pragma unroll
        for (int j = 0; j < 16; ++j) v += s_part[j];
        const int cnt = s_bcnt[0] + s_bcnt[1];
        v *= INV_SQRT_D_ / sqrtf((float)cnt);
        if (ck_mask[n * K_ + k] == 0) v = NEGINF_;
        ck_attn[n * K_ + k] = v;

        // order-preserving float encoding; ties -> smaller k (numpy first-max)
        unsigned ub = __float_as_uint(v);
        ub = (ub & 0x80000000u) ? ~ub : (ub | 0x80000000u);
        const unsigned long long pk =
            ((unsigned long long)ub << 32) | (unsigned)(K_ - 1 - k);
        atomicMax(&key[n], pk);
    }
}

// ---------------------------------------------------------------
// Kernel 3 (1024 blocks x 128): chosen-knowledge rows only.
__global__ void gather_cs_kernel(const int* __restrict__ know_tokens,
                                 const int* __restrict__ cs_ids,
                                 const int* __restrict__ use_cs_ids,
                                 const unsigned long long* __restrict__ key,
                                 const float* __restrict__ emb,
                                 float* __restrict__ full_enc,
                                 float* __restrict__ full_mask) {
    const int bid = blockIdx.x;
    const int n = bid >> 7;
    const int r = bid & 127;
    const int tid = threadIdx.x;

    const int kbest = (K_ - 1) - (int)(key[n] & 0xffffffffull);
    const int ch = (use_cs_ids[0] != 0) ? cs_ids[n] : kbest;

    const int token = know_tokens[((size_t)n * K_ + ch) * TK_ + r];
    ((float4*)(full_enc + ((size_t)n * TOUT_ + r) * D_))[tid] =
        ((const float4*)(emb + (size_t)token * D_))[tid];
    if (tid == 0) full_mask[n * TOUT_ + r] = (token != 0) ? 1.0f : 0.0f;
}

// ---------------------------------------------------------------
extern "C" void kernel_launch(void* const* d_in, const int* in_sizes, int n_in,
                              void* d_out, int out_size, void* d_ws, size_t ws_size,
                              hipStream_t stream) {
    const int*   src_tokens  = (const int*)d_in[0];   // [N,Tc]
    const int*   know_tokens = (const int*)d_in[1];   // [N,K,Tk]
    const int*   ck_mask     = (const int*)d_in[2];   // [N,K] 0/1
    const int*   cs_ids      = (const int*)d_in[3];   // [N]
    const int*   use_cs_ids  = (const int*)d_in[4];   // scalar
    const float* emb         = (const float*)d_in[5]; // [V,D]

    float* out = (float*)d_out;
    float* full_enc  = out;
    float* full_mask = out + OUT_MASK_OFF_;
    float* ck_attn   = out + OUT_ATTN_OFF_;

    // workspace: key[8] ULL | pcnt[128] int | partial[128*128] float4
    char* ws = (char*)d_ws;
    unsigned long long* key = (unsigned long long*)ws;      // 64 B
    int* pcnt       = (int*)(ws + 64);                      // 512 B
    float4* partial = (float4*)(ws + 1024);                 // 256 KB

    ctx_pool_kernel<<<POOLB_, 1024, 0, stream>>>(src_tokens, emb,
                                                 full_enc, full_mask,
                                                 partial, pcnt, key);
    know_kernel<<<N_ * K_, 1024, 0, stream>>>(know_tokens, ck_mask, emb,
                                              partial, pcnt, ck_attn, key);
    gather_cs_kernel<<<N_ * TK_, 128, 0, stream>>>(know_tokens, cs_ids,
                                                   use_cs_ids, key, emb,
                                                   full_enc, full_mask);
}

// Round 10
// 19.929 us; speedup vs baseline: 1.2885x; 1.2885x over previous
//
#include <hip/hip_runtime.h>

// Problem constants (from reference setup_inputs)
#define N_  8
#define K_  32
#define TK_ 128
#define TC_ 256
#define D_  512
#define D4_ (D_ / 4)               // 128 float4 per emb row
#define TOUT_ (TK_ + TC_)          // 384
#define NEGINF_ (-1e20f)
#define INV_SQRT_D_ 0.044194173824159216f   // 1/sqrt(512)

// d_out layout (float): full_enc [N,384,512] | full_mask [N,384] | ck_attn [N,32]
#define OUT_MASK_OFF_ 1572864
#define OUT_ATTN_OFF_ 1575936

#define QPC_ 8                      // ctx slices per row
#define QTOK_ (TC_ / QPC_)          // 32 tokens per slice
#define POOLB_ (N_ * QPC_)          // 64 pool blocks

// ---------------------------------------------------------------
// Kernel 1 (64 blocks x 1024): block (n,q) handles ctx tokens
// [q*32,(q+1)*32): pools into partial[n*8+q] (+count) AND writes those
// full_enc context rows + full_mask while the rows are in registers.
// Block 0 resets key[].
__global__ __launch_bounds__(1024) void ctx_pool_kernel(
        const int* __restrict__ src_tokens,
        const float* __restrict__ emb,
        float* __restrict__ full_enc,
        float* __restrict__ full_mask,
        float4* __restrict__ partial,        // [64][128] float4
        int* __restrict__ pcnt,              // [64]
        unsigned long long* __restrict__ key) {
    const int bid = blockIdx.x;
    const int n = bid >> 3, q = bid & 7;
    const int tid = threadIdx.x;
    const int tg = tid >> 7, lane = tid & 127;
    const float4* emb4 = (const float4*)emb;

    __shared__ int s_tok[QTOK_];
    __shared__ float4 s_red[8][D4_];   // 16 KB
    __shared__ int s_cnt[8];

    if (bid == 0 && tid < N_) key[tid] = 0ull;   // per-call reset
    if (tid < QTOK_) s_tok[tid] = src_tokens[n * TC_ + q * QTOK_ + tid];
    __syncthreads();

    float4 acc = make_float4(0.f, 0.f, 0.f, 0.f);
    int cnt = 0;
    #pragma unroll
    for (int i = 0; i < QTOK_ / 8; ++i) {        // 4 tokens per thread
        const int t = tg + i * 8;                // token slot within slice
        const int tok = s_tok[t];
        const float4 v = emb4[(size_t)tok * D4_ + lane];  // row 0 is valid
        // write-through to full_enc context region (emb[tok] regardless of pad)
        const int row = TK_ + q * QTOK_ + t;
        ((float4*)(full_enc + ((size_t)n * TOUT_ + row) * D_))[lane] = v;
        if (lane == 0) full_mask[n * TOUT_ + row] = (tok != 0) ? 1.0f : 0.0f;

        const bool use = (tok != 0);
        cnt += use ? 1 : 0;
        acc.x += use ? v.x : 0.f;
        acc.y += use ? v.y : 0.f;
        acc.z += use ? v.z : 0.f;
        acc.w += use ? v.w : 0.f;
    }
    s_red[tg][lane] = acc;
    if (lane == 0) s_cnt[tg] = cnt;
    __syncthreads();

    if (tg == 0) {
        float4 tot = s_red[0][lane];
        #pragma unroll
        for (int j = 1; j < 8; ++j) {
            const float4 v = s_red[j][lane];
            tot.x += v.x; tot.y += v.y; tot.z += v.z; tot.w += v.w;
        }
        partial[bid * D4_ + lane] = tot;
        if (lane == 0) {
            int c = 0;
            #pragma unroll
            for (int j = 0; j < 8; ++j) c += s_cnt[j];
            pcnt[bid] = c;
        }
    }
}

// ---------------------------------------------------------------
// Kernel 2 (256 blocks x 1024): block (n,k) = fused knowledge pool+dot.
// MASK-SKIP: if ck_mask[n,k]==0 the dot result is discarded by the
// reference (where -> NEGINF), so skip the 256 KB gather entirely and
// emit NEGINF + argmax key. ~Halves this kernel's memory traffic.
__global__ __launch_bounds__(1024) void know_kernel(
        const int* __restrict__ know_tokens,
        const int* __restrict__ ck_mask,
        const float* __restrict__ emb,
        const float4* __restrict__ partial,
        const int* __restrict__ pcnt,
        float* __restrict__ ck_attn,
        unsigned long long* __restrict__ key) {
    const int bid = blockIdx.x;
    const int tid = threadIdx.x;
    const int n = bid >> 5, k = bid & 31;
    const int tg = tid >> 7, lane = tid & 127;
    const float4* emb4 = (const float4*)emb;

    __shared__ float4 s_ctx[D4_];    // 2 KB
    __shared__ int s_tok[TK_];
    __shared__ float s_part[16];
    __shared__ int s_bcnt[2];

    const int msk = ck_mask[n * K_ + k];   // block-uniform

    if (msk != 0) {
        if (tid < D4_) {
            // combine the 8 ctx partials -> scaled ctx_use slice
            float4 c = partial[(n * QPC_ + 0) * D4_ + tid];
            int cc = pcnt[n * QPC_ + 0];
            #pragma unroll
            for (int qq = 1; qq < QPC_; ++qq) {
                const float4 v = partial[(n * QPC_ + qq) * D4_ + tid];
                c.x += v.x; c.y += v.y; c.z += v.z; c.w += v.w;
                cc += pcnt[n * QPC_ + qq];
            }
            const float sc = INV_SQRT_D_ / sqrtf((float)cc);
            c.x *= sc; c.y *= sc; c.z *= sc; c.w *= sc;
            s_ctx[tid] = c;

            const int tok = know_tokens[(size_t)bid * TK_ + tid];
            s_tok[tid] = tok;
            const unsigned long long b = __ballot(tok != 0);  // waves 0,1 full
            if ((tid & 63) == 0) s_bcnt[tid >> 6] = (int)__popcll(b);
        }
        __syncthreads();

        const float4 c = s_ctx[lane];
        float acc = 0.f;
        #pragma unroll
        for (int i = 0; i < TK_ / 8; ++i) {      // 16 tokens per thread
            const int tok = s_tok[tg + i * 8];
            const float4 v = emb4[(size_t)tok * D4_ + lane];  // unconditional
            const float d = v.x * c.x + v.y * c.y + v.z * c.z + v.w * c.w;
            acc += (tok != 0) ? d : 0.f;         // cndmask, no branch
        }
        #pragma unroll
        for (int off = 32; off > 0; off >>= 1) acc += __shfl_down(acc, off, 64);
        if ((tid & 63) == 0) s_part[tid >> 6] = acc;
        __syncthreads();
    }

    if (tid == 0) {
        float v;
        if (msk != 0) {
            v = 0.f;
            #pragma unroll
            for (int j = 0; j < 16; ++j) v += s_part[j];
            const int cnt = s_bcnt[0] + s_bcnt[1];
            v *= INV_SQRT_D_ / sqrtf((float)cnt);
        } else {
            v = NEGINF_;                          // exact reference value
        }
        ck_attn[n * K_ + k] = v;

        // order-preserving float encoding; ties -> smaller k (numpy first-max)
        unsigned ub = __float_as_uint(v);
        ub = (ub & 0x80000000u) ? ~ub : (ub | 0x80000000u);
        const unsigned long long pk =
            ((unsigned long long)ub << 32) | (unsigned)(K_ - 1 - k);
        atomicMax(&key[n], pk);
    }
}

// ---------------------------------------------------------------
// Kernel 3 (1024 blocks x 128): chosen-knowledge rows only.
__global__ void gather_cs_kernel(const int* __restrict__ know_tokens,
                                 const int* __restrict__ cs_ids,
                                 const int* __restrict__ use_cs_ids,
                                 const unsigned long long* __restrict__ key,
                                 const float* __restrict__ emb,
                                 float* __restrict__ full_enc,
                                 float* __restrict__ full_mask) {
    const int bid = blockIdx.x;
    const int n = bid >> 7;
    const int r = bid & 127;
    const int tid = threadIdx.x;

    const int kbest = (K_ - 1) - (int)(key[n] & 0xffffffffull);
    const int ch = (use_cs_ids[0] != 0) ? cs_ids[n] : kbest;

    const int token = know_tokens[((size_t)n * K_ + ch) * TK_ + r];
    ((float4*)(full_enc + ((size_t)n * TOUT_ + r) * D_))[tid] =
        ((const float4*)(emb + (size_t)token * D_))[tid];
    if (tid == 0) full_mask[n * TOUT_ + r] = (token != 0) ? 1.0f : 0.0f;
}

// ---------------------------------------------------------------
extern "C" void kernel_launch(void* const* d_in, const int* in_sizes, int n_in,
                              void* d_out, int out_size, void* d_ws, size_t ws_size,
                              hipStream_t stream) {
    const int*   src_tokens  = (const int*)d_in[0];   // [N,Tc]
    const int*   know_tokens = (const int*)d_in[1];   // [N,K,Tk]
    const int*   ck_mask     = (const int*)d_in[2];   // [N,K] 0/1
    const int*   cs_ids      = (const int*)d_in[3];   // [N]
    const int*   use_cs_ids  = (const int*)d_in[4];   // scalar
    const float* emb         = (const float*)d_in[5]; // [V,D]

    float* out = (float*)d_out;
    float* full_enc  = out;
    float* full_mask = out + OUT_MASK_OFF_;
    float* ck_attn   = out + OUT_ATTN_OFF_;

    // workspace: key[8] ULL | pcnt[64] int | partial[64*128] float4
    char* ws = (char*)d_ws;
    unsigned long long* key = (unsigned long long*)ws;      // 64 B
    int* pcnt       = (int*)(ws + 64);                      // 256 B
    float4* partial = (float4*)(ws + 512);                  // 128 KB

    ctx_pool_kernel<<<POOLB_, 1024, 0, stream>>>(src_tokens, emb,
                                                 full_enc, full_mask,
                                                 partial, pcnt, key);
    know_kernel<<<N_ * K_, 1024, 0, stream>>>(know_tokens, ck_mask, emb,
                                              partial, pcnt, ck_attn, key);
    gather_cs_kernel<<<N_ * TK_, 128, 0, stream>>>(know_tokens, cs_ids,
                                                   use_cs_ids, key, emb,
                                                   full_enc, full_mask);
}